// Round 3
// baseline (109.189 us; speedup 1.0000x reference)
//
#include <hip/hip_runtime.h>
#include <math.h>

#define B_DIM   4
#define C_DIM   256
#define H_DIM   64
#define W_DIM   64
#define HW_DIM  4096   // H*W
#define NREF    4

typedef unsigned short u16;
typedef __attribute__((ext_vector_type(4))) unsigned short u16x4;
typedef __attribute__((ext_vector_type(8))) short bf16x8;
typedef __attribute__((ext_vector_type(4))) float f32x4;

__device__ __forceinline__ u16 bf16_rne(float f) {
    unsigned u = __float_as_uint(f);
    u = u + 0x7FFFu + ((u >> 16) & 1u);
    return (u16)(u >> 16);
}
__device__ __forceinline__ float bf16_tof(u16 h) {
    return __uint_as_float(((unsigned)h) << 16);
}
__device__ __forceinline__ void gload16(const void* g, void* l) {
    __builtin_amdgcn_global_load_lds(
        (const __attribute__((address_space(1))) void*)g,
        (__attribute__((address_space(3))) void*)l, 16, 0, 0);
}

// ---------------------------------------------------------------------------
// x prep: (B, C, HW) f32  ->  (B*HW, C) bf16 hi + lo planes (transpose+split).
// ---------------------------------------------------------------------------
__global__ __launch_bounds__(256) void xsplit_kernel(
    const float* __restrict__ x, u16* __restrict__ xh, u16* __restrict__ xl)
{
    __shared__ float tile[64][65];
    const int b   = blockIdx.z;
    const int c0  = blockIdx.y * 64;
    const int hw0 = blockIdx.x * 64;
    const int t   = threadIdx.x;
    const int r4  = t >> 6;     // 0..3
    const int col = t & 63;

#pragma unroll
    for (int i = 0; i < 16; ++i) {
        const int row = i * 4 + r4;  // c index
        tile[row][col] = x[((size_t)b * C_DIM + c0 + row) * HW_DIM + hw0 + col];
    }
    __syncthreads();
#pragma unroll
    for (int i = 0; i < 16; ++i) {
        const int hwr = i * 4 + r4;        // hw row
        const float v = tile[col][hwr];    // [c][hw] transposed read
        const u16 h = bf16_rne(v);
        const float lo = v - bf16_tof(h);
        const size_t o = ((size_t)b * HW_DIM + hw0 + hwr) * C_DIM + c0 + col;
        xh[o] = h;
        xl[o] = bf16_rne(lo);
    }
}

// ---------------------------------------------------------------------------
// Merged Q/K/V projection kernel.
//   role = blockIdx.x % 3: 0 -> qproj tile (f32 VALU), else kv tile (MFMA).
// Interleaving puts ~1 qproj + 2 kv blocks per CU so the f32 FMA pipe and the
// MFMA pipe run concurrently (separate pipes co-schedule across waves).
// LDS: 64 KB static (kv needs it); qproj role uses the first 16 KB.
// ---------------------------------------------------------------------------
__global__ __launch_bounds__(256) void qkv_merged(
    const float* __restrict__ x,
    const u16* __restrict__ xh, const u16* __restrict__ xl,
    const float* __restrict__ Wq, const float* __restrict__ bq,
    const float* __restrict__ Wk, const float* __restrict__ bk,
    const float* __restrict__ Wv, const float* __restrict__ bv,
    float* __restrict__ Qt, float* __restrict__ Kt, float* __restrict__ Vt)
{
    __shared__ char smem[65536];

    const int bz   = blockIdx.x;
    const int t    = threadIdx.x;

    if (bz % 3 == 0) {
        // =============== Q projection: f32, bitwise round-1 chain ===========
        // 128x128 tile, 8x8 per thread; a-frag split 4+4 (2-way LDS = free).
        const int q    = bz / 3;           // 0..255
        const int mt   = q >> 1;           // 0..127 : m-tile over B*HW
        const int o0   = (q & 1) * 128;
        const int m0   = mt * 128;
        const int b    = m0 / HW_DIM;
        const int hw0  = m0 % HW_DIM;

        float (*x_s)[128] = (float(*)[128])smem;            // 8 KB
        float (*w_s)[128] = (float(*)[128])(smem + 8192);   // 8 KB

        const int tx = t & 15;   // hw group
        const int ty = t >> 4;   // o group (0..15, 8 o each)

        float acc[8][8];
#pragma unroll
        for (int i = 0; i < 8; ++i)
#pragma unroll
            for (int j = 0; j < 8; ++j) acc[i][j] = 0.0f;

        const float* xb = x + (size_t)b * C_DIM * HW_DIM;

        for (int c0 = 0; c0 < C_DIM; c0 += 16) {
            {   // x chunk: 16 c-rows x 128 hw, coalesced
                const int cr  = t >> 4;
                const int col = (t & 15) * 8;
                const float* src = xb + (size_t)(c0 + cr) * HW_DIM + hw0 + col;
                *(float4*)&x_s[cr][col]     = *(const float4*)(src);
                *(float4*)&x_s[cr][col + 4] = *(const float4*)(src + 4);
            }
            {   // W chunk: 128 o-rows x 16 c, transposed into LDS
                const int r  = t >> 1;
                const int cc = (t & 1) * 8;
                const float* src = Wq + (size_t)(o0 + r) * C_DIM + c0 + cc;
                float4 v0 = *(const float4*)(src);
                float4 v1 = *(const float4*)(src + 4);
                w_s[cc + 0][r] = v0.x; w_s[cc + 1][r] = v0.y;
                w_s[cc + 2][r] = v0.z; w_s[cc + 3][r] = v0.w;
                w_s[cc + 4][r] = v1.x; w_s[cc + 5][r] = v1.y;
                w_s[cc + 6][r] = v1.z; w_s[cc + 7][r] = v1.w;
            }
            __syncthreads();

#pragma unroll
            for (int c = 0; c < 16; ++c) {
                float a[8], w[8];
                *(float4*)&a[0] = *(const float4*)&x_s[c][tx * 4];        // rows tx*4..+3
                *(float4*)&a[4] = *(const float4*)&x_s[c][64 + tx * 4];   // rows 64+tx*4..+3
                *(float4*)&w[0] = *(const float4*)&w_s[c][ty * 8];
                *(float4*)&w[4] = *(const float4*)&w_s[c][ty * 8 + 4];
#pragma unroll
                for (int i = 0; i < 8; ++i)
#pragma unroll
                    for (int j = 0; j < 8; ++j)
                        acc[i][j] = fmaf(a[i], w[j], acc[i][j]);   // ascending c: bitwise == r1/r2
            }
            __syncthreads();
        }

        float bias[8];
#pragma unroll
        for (int j = 0; j < 8; ++j) bias[j] = bq[o0 + ty * 8 + j];

        float* outb = Qt + ((size_t)b * HW_DIM + hw0) * C_DIM + o0;
#pragma unroll
        for (int i = 0; i < 8; ++i) {
            const int hw_l = (i < 4) ? (tx * 4 + i) : (64 + tx * 4 + (i - 4));
            float* dst = outb + (size_t)hw_l * C_DIM + ty * 8;
            float4 v0, v1;
            v0.x = acc[i][0] + bias[0]; v0.y = acc[i][1] + bias[1];
            v0.z = acc[i][2] + bias[2]; v0.w = acc[i][3] + bias[3];
            v1.x = acc[i][4] + bias[4]; v1.y = acc[i][5] + bias[5];
            v1.z = acc[i][6] + bias[6]; v1.w = acc[i][7] + bias[7];
            *(float4*)(dst)     = v0;
            *(float4*)(dst + 4) = v1;
        }
    } else {
        // =============== K/V projection: 3-pass split-bf16 MFMA =============
        const int k    = (bz / 3) * 2 + (bz % 3) - 1;   // 0..511
        const int mat  = k & 1;
        const int n0   = ((k >> 1) & 1) * 128;
        const int m0   = (k >> 2) * 128;

        const float* Wm  = mat ? Wv : Wk;
        const float* bm  = mat ? bv : bk;
        float*       Out = mat ? Vt : Kt;

        u16* Ah = (u16*)smem;
        u16* Al = Ah + 8192;
        u16* Bh = Ah + 16384;
        u16* Bl = Ah + 24576;

        const int lane = t & 63;
        const int wv   = t >> 6;
        const int wm   = (wv >> 1) * 64;
        const int wn   = (wv & 1) * 64;

        f32x4 acc[4][4] = {};

        for (int kt = 0; kt < 4; ++kt) {
            const int k0 = kt * 64;

            // stage A hi/lo: linear LDS dest, inverse-swizzled global src
#pragma unroll
            for (int it = 0; it < 4; ++it) {
                const int s   = it * 256 + t;
                const int row = s >> 3;
                const int sch = (s & 7) ^ (row & 7);
                const size_t goff = (size_t)(m0 + row) * C_DIM + k0 + sch * 8;
                gload16(xh + goff, (char*)Ah + s * 16);
                gload16(xl + goff, (char*)Al + s * 16);
            }
            // stage B: read W f32, split, swizzled ds_write
#pragma unroll
            for (int i = 0; i < 8; ++i) {
                const int f  = i * 256 + t;
                const int r  = f >> 4;
                const int c4 = (f & 15) * 4;
                const float4 w4 = *(const float4*)(Wm + (size_t)(n0 + r) * C_DIM + k0 + c4);
                u16x4 h, l;
                h.x = bf16_rne(w4.x); l.x = bf16_rne(w4.x - bf16_tof(h.x));
                h.y = bf16_rne(w4.y); l.y = bf16_rne(w4.y - bf16_tof(h.y));
                h.z = bf16_rne(w4.z); l.z = bf16_rne(w4.z - bf16_tof(h.z));
                h.w = bf16_rne(w4.w); l.w = bf16_rne(w4.w - bf16_tof(h.w));
                const int chunk = c4 >> 3;
                const int sub   = (c4 & 7) * 2;
                const int boff  = r * 128 + ((chunk ^ (r & 7)) * 16) + sub;
                *(u16x4*)((char*)Bh + boff) = h;
                *(u16x4*)((char*)Bl + boff) = l;
            }
            __syncthreads();

#pragma unroll
            for (int ks = 0; ks < 2; ++ks) {
                bf16x8 afh[4], afl[4], bfh[4], bfl[4];
#pragma unroll
                for (int mt2 = 0; mt2 < 4; ++mt2) {
                    const int row = wm + mt2 * 16 + (lane & 15);
                    const int ch  = (ks * 4 + (lane >> 4)) ^ (row & 7);
                    const int off = row * 128 + ch * 16;
                    afh[mt2] = *(const bf16x8*)((const char*)Ah + off);
                    afl[mt2] = *(const bf16x8*)((const char*)Al + off);
                }
#pragma unroll
                for (int nt = 0; nt < 4; ++nt) {
                    const int row = wn + nt * 16 + (lane & 15);
                    const int ch  = (ks * 4 + (lane >> 4)) ^ (row & 7);
                    const int off = row * 128 + ch * 16;
                    bfh[nt] = *(const bf16x8*)((const char*)Bh + off);
                    bfl[nt] = *(const bf16x8*)((const char*)Bl + off);
                }
#pragma unroll
                for (int mt2 = 0; mt2 < 4; ++mt2)
#pragma unroll
                    for (int nt = 0; nt < 4; ++nt) {
                        acc[mt2][nt] = __builtin_amdgcn_mfma_f32_16x16x32_bf16(afh[mt2], bfh[nt], acc[mt2][nt], 0, 0, 0);
                        acc[mt2][nt] = __builtin_amdgcn_mfma_f32_16x16x32_bf16(afh[mt2], bfl[nt], acc[mt2][nt], 0, 0, 0);
                        acc[mt2][nt] = __builtin_amdgcn_mfma_f32_16x16x32_bf16(afl[mt2], bfh[nt], acc[mt2][nt], 0, 0, 0);
                    }
            }
            __syncthreads();
        }

        const int col = lane & 15;
        const int rg  = (lane >> 4) * 4;
#pragma unroll
        for (int nt = 0; nt < 4; ++nt) {
            const int n = n0 + wn + nt * 16 + col;
            const float bias = bm[n];
#pragma unroll
            for (int mt2 = 0; mt2 < 4; ++mt2) {
                const int m = m0 + wm + mt2 * 16 + rg;
#pragma unroll
                for (int r = 0; r < 4; ++r)
                    Out[(size_t)(m + r) * C_DIM + n] = acc[mt2][nt][r] + bias;
            }
        }
    }
}

// ---------------------------------------------------------------------------
// Stage 2: fused offsets -> indices -> gather K -> softmax -> gather V -> out.
// ---------------------------------------------------------------------------
__global__ __launch_bounds__(1024) void attn_kernel(
    const float* __restrict__ Qt,   // (B, HW, C)
    const float* __restrict__ Kt,
    const float* __restrict__ Vt,
    const float* __restrict__ Woff, // (8, C)
    const float* __restrict__ boff, // (8,)
    float* __restrict__ out)        // (B, C, HW)
{
    __shared__ float trans[16][260];

    const int t    = threadIdx.x;
    const int wave = t >> 6;
    const int lane = t & 63;

    const int pix0 = blockIdx.x * 16;
    const int b    = pix0 / HW_DIM;
    const int hw   = (pix0 % HW_DIM) + wave;
    const int h    = hw >> 6;
    const int w    = hw & 63;

    const float* qrow = Qt + ((size_t)b * HW_DIM + hw) * C_DIM;
    float q[4];
    *(float4*)q = *(const float4*)(qrow + lane * 4);

    float part[8];
#pragma unroll
    for (int j = 0; j < 8; ++j) {
        float4 wv = *(const float4*)(Woff + j * C_DIM + lane * 4);
        part[j] = fmaf(q[3], wv.w, fmaf(q[2], wv.z, fmaf(q[1], wv.y, q[0] * wv.x)));
    }
#pragma unroll
    for (int off = 1; off < 64; off <<= 1) {
#pragma unroll
        for (int j = 0; j < 8; ++j) part[j] += __shfl_xor(part[j], off);
    }

    int idx[NREF];
#pragma unroll
    for (int n = 0; n < NREF; ++n) {
        const float ox = part[2 * n]     + boff[2 * n];
        const float oy = part[2 * n + 1] + boff[2 * n + 1];
        int rx = (int)rintf((float)w + ox);
        int ry = (int)rintf((float)h + oy);
        rx = min(max(rx, 0), W_DIM - 1);
        ry = min(max(ry, 0), H_DIM - 1);
        idx[n] = ry * W_DIM + rx;
    }

    float logit[NREF];
#pragma unroll
    for (int n = 0; n < NREF; ++n) {
        const float* krow = Kt + ((size_t)b * HW_DIM + idx[n]) * C_DIM;
        float4 kv = *(const float4*)(krow + lane * 4);
        float lp = fmaf(q[3], kv.w, fmaf(q[2], kv.z, fmaf(q[1], kv.y, q[0] * kv.x)));
#pragma unroll
        for (int off = 1; off < 64; off <<= 1) lp += __shfl_xor(lp, off);
        logit[n] = lp;
    }

    float mx = fmaxf(fmaxf(logit[0], logit[1]), fmaxf(logit[2], logit[3]));
    float e[NREF], s = 0.0f;
#pragma unroll
    for (int n = 0; n < NREF; ++n) { e[n] = expf(logit[n] - mx); s += e[n]; }
    float wgt[NREF];
#pragma unroll
    for (int n = 0; n < NREF; ++n) wgt[n] = e[n] / s;

    float o4[4] = {0.f, 0.f, 0.f, 0.f};
#pragma unroll
    for (int n = 0; n < NREF; ++n) {
        const float* vrow = Vt + ((size_t)b * HW_DIM + idx[n]) * C_DIM;
        float4 vv = *(const float4*)(vrow + lane * 4);
        o4[0] = fmaf(wgt[n], vv.x, o4[0]);
        o4[1] = fmaf(wgt[n], vv.y, o4[1]);
        o4[2] = fmaf(wgt[n], vv.z, o4[2]);
        o4[3] = fmaf(wgt[n], vv.w, o4[3]);
    }

    *(float4*)&trans[wave][lane * 4] = *(float4*)o4;
    __syncthreads();

    float* ob = out + (size_t)b * C_DIM * HW_DIM + (pix0 % HW_DIM);
    const int px = t & 15;
#pragma unroll
    for (int cc = 0; cc < C_DIM; cc += 64) {
        const int c = cc + (t >> 4);
        ob[(size_t)c * HW_DIM + px] = trans[px][c];
    }
}

// ---------------------------------------------------------------------------
extern "C" void kernel_launch(void* const* d_in, const int* in_sizes, int n_in,
                              void* d_out, int out_size, void* d_ws, size_t ws_size,
                              hipStream_t stream) {
    const float* x    = (const float*)d_in[0];
    const float* Wq   = (const float*)d_in[1];
    const float* bq   = (const float*)d_in[2];
    const float* Wk   = (const float*)d_in[3];
    const float* bk   = (const float*)d_in[4];
    const float* Wv   = (const float*)d_in[5];
    const float* bv   = (const float*)d_in[6];
    const float* Woff = (const float*)d_in[7];
    const float* boff = (const float*)d_in[8];
    float* out = (float*)d_out;

    // Workspace (ws is 256 MiB; we use 64 MiB, all regions disjoint):
    //   [0,16M)   Kt f32 (B*HW, C)
    //   [16,32M)  Vt f32
    //   [32,48M)  Qt f32
    //   [48,56M)  xh bf16 plane
    //   [56,64M)  xl bf16 plane
    char* ws = (char*)d_ws;
    float* Kt = (float*)ws;
    float* Vt = (float*)(ws + (size_t)16 * 1024 * 1024);
    float* Qt = (float*)(ws + (size_t)32 * 1024 * 1024);
    u16*   xh = (u16*)  (ws + (size_t)48 * 1024 * 1024);
    u16*   xl = (u16*)  (ws + (size_t)56 * 1024 * 1024);

    // 1) transpose + bf16-split x (feeds only the kv role)
    xsplit_kernel<<<dim3(HW_DIM / 64, C_DIM / 64, B_DIM), dim3(256), 0, stream>>>(x, xh, xl);
    // 2) merged Q (f32 VALU) + K/V (MFMA): 256 qproj + 512 kv = 768 blocks,
    //    role-interleaved so VALU and MFMA pipes co-schedule on each CU.
    qkv_merged<<<dim3(768), dim3(256), 0, stream>>>(
        x, xh, xl, Wq, bq, Wk, bk, Wv, bv, Qt, Kt, Vt);
    // 3) fused deformable attention
    attn_kernel<<<dim3((B_DIM * HW_DIM) / 16), dim3(1024), 0, stream>>>(
        Qt, Kt, Vt, Woff, boff, out);
}